// Round 8
// baseline (220.431 us; speedup 1.0000x reference)
//
#include <hip/hip_runtime.h>
#include <stdint.h>

#define NUM_B 128
#define NUM_P 8732
#define NUM_G 16
#define NUM_C 21
#define THR 0.5f
#define PB 35            // ceil(8732/256)
#define SEL_T 1024
#define SEL_W (SEL_T / 64)
#define GROW 96          // dwords per gbox row: x1[16],y1[16],x2[16],y2[16],area[16],lab[4],pad

__device__ __forceinline__ unsigned int f2u(float f) {
    unsigned int b = __float_as_uint(f);
    return (b & 0x80000000u) ? ~b : (b | 0x80000000u);
}
__device__ __forceinline__ float u2f(unsigned int u) {
    unsigned int b = (u & 0x80000000u) ? (u & 0x7FFFFFFFu) : ~u;
    return __uint_as_float(b);
}

// async global->LDS, 16B per lane; LDS dst = wave-uniform base + lane*16
__device__ __forceinline__ void gl_lds16(const float* gsrc, float* ldst) {
    __builtin_amdgcn_global_load_lds(
        (__attribute__((address_space(1))) void*)gsrc,
        (__attribute__((address_space(3))) void*)ldst,
        16, 0, 0);
}

// IoU core — the SINGLE source of truth. fused's per-prior argmax, select's
// per-gt argmax, and select's delta-patch all call this with identical
// float inputs -> bit-identical results.
__device__ __forceinline__ float iou1(float x1, float y1, float x2, float y2, float ar,
                                      float bx1, float by1, float bx2, float by2,
                                      float areaB) {
    float dx = fminf(x2, bx2) - fmaxf(x1, bx1);
    float dy = fminf(y2, by2) - fmaxf(y1, by1);
    dx = fmaxf(dx, 0.f); dy = fmaxf(dy, 0.f);
    float inter = dx * dy;
    float uni = ar + areaB - inter;
    return inter * __builtin_amdgcn_rcpf(uni);
}

// per-prior best gt (strict > => first-index argmax)
__device__ __forceinline__ void match_row(const float* __restrict__ rb, float4 pr,
                                          float& ov, int& j0) {
    float bx1 = pr.x - pr.z * 0.5f, by1 = pr.y - pr.w * 0.5f;
    float bx2 = pr.x + pr.z * 0.5f, by2 = pr.y + pr.w * 0.5f;
    float areaB = (bx2 - bx1) * (by2 - by1);
    ov = -1.0f; j0 = 0;
    #pragma unroll
    for (int j = 0; j < NUM_G; ++j) {
        float v = iou1(rb[j], rb[16 + j], rb[32 + j], rb[48 + j], rb[64 + j],
                       bx1, by1, bx2, by2, areaB);
        if (v > ov) { ov = v; j0 = j; }
    }
}

// smooth-L1 sum for prior (pr, loc row ld) vs target row tgj (11 floats, global)
__device__ __forceinline__ float sl1_sum(const float* __restrict__ ld,
                                         float4 pr, const float* __restrict__ tgj) {
    float t[10];
    t[0] = ((tgj[0] + tgj[2]) * 0.5f - pr.x) / (0.1f * pr.z);
    t[1] = ((tgj[1] + tgj[3]) * 0.5f - pr.y) / (0.1f * pr.w);
    t[2] = __logf((tgj[2] - tgj[0]) / pr.z) / 0.2f;
    t[3] = __logf((tgj[3] - tgj[1]) / pr.w) / 0.2f;
    t[4] = __logf(tgj[4] / pr.z + 0.1f) / 0.2f;
    t[5] = __logf(tgj[5] / pr.w + 0.1f) / 0.2f;
    t[6] = __logf(tgj[6] / pr.z + 0.1f) / 0.2f;
    t[7] = __logf(tgj[7] / pr.w + 0.1f) / 0.2f;
    t[8] = (tgj[8] - pr.x) / (0.1f * pr.z);
    t[9] = (tgj[9] - pr.y) / (0.1f * pr.w);
    float s = 0.f;
    #pragma unroll
    for (int d = 0; d < 10; ++d) {
        float df = ld[d] - t[d];
        float ad = fabsf(df);
        s += (ad < 1.f) ? 0.5f * df * df : (ad - 0.5f);
    }
    return s;
}

// single-pass LSE (logits ~ N(0,1): no overflow risk)
__device__ __forceinline__ float lse21(const float* cv) {
    float s = 0.f;
    #pragma unroll
    for (int c = 0; c < NUM_C; ++c) s += __expf(cv[c]);
    return __logf(s);
}

// ---------------------------------------------------------------- pre: gbox SoA + ticket
__global__ void pre_kernel(const float* __restrict__ targets,
                           float* __restrict__ gbox,
                           unsigned int* __restrict__ ticket) {
    int idx = blockIdx.x * 256 + threadIdx.x;
    if (idx < NUM_B * NUM_G) {
        int b = idx >> 4, j = idx & 15;
        const float* t = targets + (size_t)idx * 11;
        float x1 = t[0], y1 = t[1], x2 = t[2], y2 = t[3];
        float* rb = gbox + (size_t)b * GROW;
        rb[j]      = x1;
        rb[16 + j] = y1;
        rb[32 + j] = x2;
        rb[48 + j] = y2;
        rb[64 + j] = (x2 - x1) * (y2 - y1);
    }
    if (idx < NUM_B * 4) {
        int b = idx >> 2, w = idx & 3;
        unsigned int lw = 0;
        #pragma unroll
        for (int e = 0; e < 4; ++e) {
            const float* t = targets + (size_t)(b * NUM_G + w * 4 + e) * 11;
            unsigned int lab = (unsigned int)((int)t[10] + 1);
            lw |= lab << (8 * e);
        }
        ((unsigned int*)(gbox + (size_t)b * GROW))[80 + w] = lw;
    }
    if (idx == 0) *ticket = 0u;
}

// ---------------------------------------------------------------- fused match + loss (lean)
__global__ void __launch_bounds__(256) fused_kernel(
        const float* __restrict__ loc_data,
        const float* __restrict__ conf_data,
        const float* __restrict__ priors,
        const float* __restrict__ gbox,
        const float* __restrict__ targets,
        float* __restrict__ lc,
        float4* __restrict__ part) {
    int b    = blockIdx.y;
    int bx   = blockIdx.x;
    int tid  = threadIdx.x;
    int base = bx * 256;
    int i    = base + tid;
    bool valid = (i < NUM_P);
    int ic   = valid ? i : (NUM_P - 1);
    int lane = tid & 63;
    int wave = tid >> 6;

    __shared__ float sconf[256 * NUM_C];   // 21504 B
    __shared__ float wll[4], wpc[4];
    __shared__ unsigned int wcnt[4];

    // ---- stage conf (async 1KiB wave-chunks on full blocks)
    const float* cbase = conf_data + ((size_t)b * NUM_P + base) * NUM_C;
    int cnt_p = NUM_P - base; if (cnt_p > 256) cnt_p = 256;
    if (cnt_p == 256) {
        #pragma unroll
        for (int c = 0; c < 21; ++c)
            if ((c & 3) == wave)
                gl_lds16(cbase + (c << 8) + lane * 4, &sconf[c << 8]);
    } else {
        int tot = cnt_p * NUM_C;
        for (int x = tid; x < tot; x += 256) sconf[x] = cbase[x];
    }

    // ---- per-prior matching (gt constants via uniform/scalar loads; no LDS)
    const float* rb = gbox + (size_t)b * GROW;
    float4 pr = ((const float4*)priors)[ic];
    float ov; int j0;
    match_row(rb, pr, ov, j0);
    __syncthreads();   // B1: conf resident (barrier drains vmcnt)

    // ---- loss terms
    float ll = 0.f, pc = 0.f; unsigned int cnt = 0u;
    if (valid) {
        bool pos = ov >= THR;
        unsigned int lw = ((const unsigned int*)rb)[80 + (j0 >> 2)];
        int conf_t = pos ? (int)((lw >> ((j0 & 3) * 8)) & 0xffu) : 0;  // label+1 packed
        const float* cv = &sconf[tid * NUM_C];   // gcd(21,32)=1 -> conflict-free
        float lse = lse21(cv);
        float lca = lse - cv[conf_t];
        lc[(size_t)b * NUM_P + i] = pos ? 0.f : lca;
        if (pos) {
            cnt = 1u; pc = lca;
            ll = sl1_sum(loc_data + ((size_t)b * NUM_P + i) * 10, pr,
                         targets + (size_t)(b * NUM_G + j0) * 11);
        }
    }
    for (int off = 32; off > 0; off >>= 1) {
        ll  += __shfl_down(ll, (unsigned)off, 64);
        pc  += __shfl_down(pc, (unsigned)off, 64);
        cnt += __shfl_down(cnt, (unsigned)off, 64);
    }
    if ((tid & 63) == 0) { wll[wave] = ll; wpc[wave] = pc; wcnt[wave] = cnt; }
    __syncthreads();   // B2
    if (tid == 0) {
        float a = 0.f, c = 0.f; unsigned int n = 0u;
        #pragma unroll
        for (int w = 0; w < 4; ++w) { a += wll[w]; c += wpc[w]; n += wcnt[w]; }
        part[(size_t)b * PB + bx] = make_float4(a, c, (float)n, 0.f);  // no atomics
    }
}

// ---------------------------------------------------------------- select: row argmax + patch + radix top-k
__global__ void __launch_bounds__(SEL_T) select_kernel(
        const float* __restrict__ loc_data,
        const float* __restrict__ conf_data,
        const float* __restrict__ priors,
        const float* __restrict__ gbox,
        const float* __restrict__ targets,
        const float* __restrict__ lc,
        const float4* __restrict__ part,
        float* __restrict__ row_ll_f,
        float* __restrict__ row_loss_c,
        unsigned int* __restrict__ row_pos_f,
        unsigned int* __restrict__ ticket,
        float* __restrict__ out) {
    int b   = blockIdx.x;
    int tid = threadIdx.x;
    int wv  = tid >> 6;

    __shared__ unsigned int su[NUM_P];               // 34928 B
    __shared__ unsigned int whist[SEL_W * 257];      // 16448 B
    __shared__ unsigned int stot[256];
    __shared__ unsigned int sbuf0[256], sbuf1[256];
    __shared__ unsigned long long wred[SEL_W][NUM_G];// 2048 B
    __shared__ unsigned int s_prefix;
    __shared__ int s_kk;
    __shared__ float wsum[SEL_W];
    __shared__ int s_last;
    __shared__ int s_pidx[NUM_G];
    __shared__ float s_dll, s_dpc;
    __shared__ int s_dcnt, s_np;
    __shared__ int s_patch[NUM_G];
    __shared__ float s_rll, s_rpc, s_rcnt;

    const float* rb = gbox + (size_t)b * GROW;
    const unsigned int* labw = (const unsigned int*)rb + 80;
    const float* lcrow = lc + (size_t)b * NUM_P;

    // ---- issue lc staging loads early (latency overlap with argmax VALU)
    float lv[9];
    #pragma unroll
    for (int m = 0; m < 9; ++m) {
        int idx = tid + m * SEL_T;
        lv[m] = (idx < NUM_P) ? lcrow[idx] : 0.f;
    }

    // ---- row partial sums (wave 0)
    if (tid < 64) {
        float rll = 0.f, rpc = 0.f, rcn = 0.f;
        if (tid < PB) {
            float4 p4 = part[(size_t)b * PB + tid];
            rll = p4.x; rpc = p4.y; rcn = p4.z;
        }
        for (int off = 32; off > 0; off >>= 1) {
            rll += __shfl_down(rll, (unsigned)off, 64);
            rpc += __shfl_down(rpc, (unsigned)off, 64);
            rcn += __shfl_down(rcn, (unsigned)off, 64);
        }
        if (tid == 0) { s_rll = rll; s_rpc = rpc; s_rcnt = rcn; }
    }
    if (tid == 0) { s_dll = 0.f; s_dpc = 0.f; s_dcnt = 0; s_np = 0; }

    // ---- per-gt argmax over this row's priors (recomputed IoUs)
    float gmx[NUM_G]; int gix[NUM_G];
    #pragma unroll
    for (int j = 0; j < NUM_G; ++j) { gmx[j] = -1.f; gix[j] = 0; }
    for (int m = 0; m < 9; ++m) {
        int idx = tid + m * SEL_T;
        if (idx < NUM_P) {
            float4 pr = ((const float4*)priors)[idx];
            float bx1 = pr.x - pr.z * 0.5f, by1 = pr.y - pr.w * 0.5f;
            float bx2 = pr.x + pr.z * 0.5f, by2 = pr.y + pr.w * 0.5f;
            float areaB = (bx2 - bx1) * (by2 - by1);
            #pragma unroll
            for (int j = 0; j < NUM_G; ++j) {
                float v = iou1(rb[j], rb[16 + j], rb[32 + j], rb[48 + j], rb[64 + j],
                               bx1, by1, bx2, by2, areaB);
                if (v > gmx[j]) { gmx[j] = v; gix[j] = idx; }  // strict > => first idx
            }
        }
    }
    // pack (iou, ~idx) and wave-reduce; ties -> smallest prior index
    #pragma unroll
    for (int j = 0; j < NUM_G; ++j) {
        unsigned long long pk = ((unsigned long long)f2u(gmx[j]) << 32) |
                                (unsigned long long)(0xFFFFFFFFu - (unsigned int)gix[j]);
        for (int off = 32; off > 0; off >>= 1) {
            unsigned long long o = __shfl_down(pk, (unsigned)off, 64);
            pk = (o > pk) ? o : pk;
        }
        if ((tid & 63) == 0) wred[wv][j] = pk;
    }

    // ---- stage su into LDS
    #pragma unroll
    for (int m = 0; m < 9; ++m) {
        int idx = tid + m * SEL_T;
        if (idx < NUM_P) su[idx] = f2u(lv[m]);
    }
    __syncthreads();   // wred + su + s_r* ready

    if (tid < NUM_G) {
        unsigned long long mx = 0ull;
        #pragma unroll
        for (int w = 0; w < SEL_W; ++w) {
            unsigned long long v = wred[w][tid];
            mx = (v > mx) ? v : mx;
        }
        s_pidx[tid] = (int)(0xFFFFFFFFu - (unsigned int)(mx & 0xFFFFFFFFull));
    }
    __syncthreads();

    // ---- lanes 0..15: override delta-patch (later j wins on duplicate priors)
    if (tid < NUM_G) {
        int j  = tid;
        int ii = s_pidx[j];
        bool winner = true;
        for (int j2 = j + 1; j2 < NUM_G; ++j2)
            if (s_pidx[j2] == ii) winner = false;
        if (winner) {
            float4 prr = ((const float4*)priors)[ii];
            float ov0; int jj0;
            match_row(rb, prr, ov0, jj0);        // bit-identical to fused
            bool pos0 = ov0 >= THR;
            const float* cd = conf_data + ((size_t)b * NUM_P + ii) * NUM_C;
            float cv[NUM_C];
            for (int c = 0; c < NUM_C; ++c) cv[c] = cd[c];
            float lse = lse21(cv);
            const float* ld = loc_data + ((size_t)b * NUM_P + ii) * 10;
            int labn = (int)((labw[j >> 2]  >> ((j  & 3) * 8)) & 0xffu);
            float lca_new = lse - cv[labn];
            float ll_new  = sl1_sum(ld, prr, targets + (size_t)(b * NUM_G + j) * 11);
            if (pos0) {
                int labo = (int)((labw[jj0 >> 2] >> ((jj0 & 3) * 8)) & 0xffu);
                float lca_old = lse - cv[labo];
                float ll_old  = sl1_sum(ld, prr, targets + (size_t)(b * NUM_G + jj0) * 11);
                atomicAdd(&s_dpc, lca_new - lca_old);
                atomicAdd(&s_dll, ll_new - ll_old);
            } else {
                atomicAdd(&s_dpc, lca_new);
                atomicAdd(&s_dll, ll_new);
                atomicAdd(&s_dcnt, 1);
                int e = atomicAdd(&s_np, 1);
                s_patch[e] = ii;
            }
        }
    }
    __syncthreads();
    if (tid < s_np) su[s_patch[tid]] = 0x80000000u;   // f2u(0): leave the neg pool
    __syncthreads();

    int npos = (int)s_rcnt + s_dcnt;
    int k = 3 * npos; if (k > NUM_P - 1) k = NUM_P - 1;

    float negsum = 0.f;
    if (k > 0) {
        if (tid == 0) { s_prefix = 0u; s_kk = k; }
        __syncthreads();

        for (int pass = 0; pass < 4; ++pass) {
            int shift = 24 - 8 * pass;
            for (int x = tid; x < SEL_W * 257; x += SEL_T) whist[x] = 0u;
            __syncthreads();
            unsigned int prefix = s_prefix;
            int kkc = s_kk;
            unsigned int hmask = (pass == 0) ? 0u : (0xFFFFFFFFu << (shift + 8));
            for (int idx = tid; idx < NUM_P; idx += SEL_T) {
                unsigned int u = su[idx];
                if ((u & hmask) == prefix)
                    atomicAdd(&whist[wv * 257 + ((u >> shift) & 255u)], 1u);
            }
            __syncthreads();
            if (tid < 256) {
                unsigned int t = 0;
                #pragma unroll
                for (int w = 0; w < SEL_W; ++w) t += whist[w * 257 + tid];
                stot[tid] = t;
                sbuf0[tid] = t;
            }
            __syncthreads();
            // suffix inclusive scan (Hillis-Steele)
            unsigned int* src = sbuf0;
            unsigned int* dst = sbuf1;
            for (int off = 1; off < 256; off <<= 1) {
                if (tid < 256)
                    dst[tid] = src[tid] + ((tid + off < 256) ? src[tid + off] : 0u);
                __syncthreads();
                unsigned int* tmp = src; src = dst; dst = tmp;
            }
            if (tid < 256) {
                unsigned int Sself = src[tid];
                unsigned int Snext = Sself - stot[tid];
                if ((int)Snext < kkc && kkc <= (int)Sself) {
                    s_prefix = prefix | ((unsigned int)tid << shift);
                    s_kk = kkc - (int)Snext;
                }
            }
            __syncthreads();
        }

        unsigned int Tu = s_prefix;
        int m = s_kk;
        float local = 0.f;
        for (int idx = tid; idx < NUM_P; idx += SEL_T) {
            unsigned int u = su[idx];
            if (u > Tu) local += u2f(u);
        }
        for (int off = 32; off > 0; off >>= 1)
            local += __shfl_down(local, (unsigned)off, 64);
        if ((tid & 63) == 0) wsum[wv] = local;
        __syncthreads();
        if (tid == 0) {
            float ssum = 0.f;
            #pragma unroll
            for (int w = 0; w < SEL_W; ++w) ssum += wsum[w];
            negsum = ssum + (float)m * u2f(Tu);
        }
    }

    if (tid == 0) {
        row_ll_f[b]   = s_rll + s_dll;
        row_pos_f[b]  = (unsigned int)npos;
        row_loss_c[b] = (s_rpc + s_dpc) + negsum;
        __threadfence();
        unsigned int t = atomicAdd(ticket, 1u);
        s_last = (t == NUM_B - 1) ? 1 : 0;
    }
    __syncthreads();

    if (s_last) {
        float l = 0.f, c = 0.f, n = 0.f;
        if (tid < NUM_B) {
            l = atomicAdd(&row_ll_f[tid], 0.f);
            c = atomicAdd(&row_loss_c[tid], 0.f);
            n = (float)atomicAdd(&row_pos_f[tid], 0u);
        }
        for (int off = 32; off > 0; off >>= 1) {
            l += __shfl_down(l, (unsigned)off, 64);
            c += __shfl_down(c, (unsigned)off, 64);
            n += __shfl_down(n, (unsigned)off, 64);
        }
        __shared__ float fl[2], fc[2], fn[2];
        if (tid < NUM_B && (tid & 63) == 0) { fl[wv] = l; fc[wv] = c; fn[wv] = n; }
        __syncthreads();
        if (tid == 0) {
            float L = fl[0] + fl[1], C = fc[0] + fc[1], N = fn[0] + fn[1];
            out[0] = L / N;
            out[1] = C / N;
        }
    }
}

extern "C" void kernel_launch(void* const* d_in, const int* in_sizes, int n_in,
                              void* d_out, int out_size, void* d_ws, size_t ws_size,
                              hipStream_t stream) {
    const float* loc_data  = (const float*)d_in[0];
    const float* conf_data = (const float*)d_in[1];
    const float* priors    = (const float*)d_in[2];
    const float* targets   = (const float*)d_in[3];
    float* out = (float*)d_out;

    char* ws = (char*)d_ws;
    size_t off = 0;
    float* lc = (float*)(ws + off); off += (size_t)NUM_B * NUM_P * sizeof(float);
    float4* part = (float4*)(ws + off); off += (size_t)NUM_B * PB * sizeof(float4);
    float* gbox = (float*)(ws + off); off += (size_t)NUM_B * GROW * sizeof(float);
    float* row_ll_f = (float*)(ws + off); off += NUM_B * sizeof(float);
    float* row_loss_c = (float*)(ws + off); off += NUM_B * sizeof(float);
    unsigned int* row_pos_f = (unsigned int*)(ws + off); off += NUM_B * sizeof(unsigned int);
    unsigned int* ticket = (unsigned int*)(ws + off); off += sizeof(unsigned int);

    pre_kernel<<<8, 256, 0, stream>>>(targets, gbox, ticket);
    fused_kernel<<<dim3(PB, NUM_B), 256, 0, stream>>>(
        loc_data, conf_data, priors, gbox, targets, lc, part);
    select_kernel<<<NUM_B, SEL_T, 0, stream>>>(
        loc_data, conf_data, priors, gbox, targets, lc, part,
        row_ll_f, row_loss_c, row_pos_f, ticket, out);
}